// Round 13
// baseline (4203.172 us; speedup 1.0000x reference)
//
#include <hip/hip_runtime.h>
#include <stdint.h>

// AttentionBasedRewiring: sim = (x@Wq+bq) @ (x@Wk+bk)^T, top-8 per row.
// out[0 .. N*8)     = top-8 scores (fp32, descending)
// out[N*8 .. 2*N*8) = top-8 indices, written as float values
//
// FROZEN (bit-exact vs golden, r5): proj_kernel's fp32 sequential-fmaf
// chain and the rescore fp32 sequential-fmaf chain + stable top-8 select
// (score desc, index asc). Candidates only need to be a superset.
//
// Round 13: kill the AGPR-shuttle tax (r12: VGPR=64 -> tp in AGPRs, med3
// asm "v" constraints forced accvgpr_read/write per op -> 2.15x VALU
// inflation, measured 3.5M vs 1.6M static issue-cycles).
//   * med3 in plain C: T[s] = max(T[s], min(p, T[s-1])) (fuses to
//     v_med3_u32, no asm operand constraints)
//   * __launch_bounds__(256,4): 128-reg unified budget; live state ~114
//     fits -> allocator keeps tp in VGPRs (no split, no spill).
//     Tripwires: VGPR=64 => split persisted; WRITE_SIZE>>13MB => spill.
//
// ws: q32 [0,33.5M) | k32 [33.5,67.1M) | cand48 [67.1,79.7M) | Kf8 [79.7,88.1M)

#define N_NODES 65536
#define D_IN    512
#define H_DIM   128
#define TOPK    8
#define NCH     24                     // candidates per column-half
#define NC      48                     // union per row
#define CTILE   128
#define NT      (N_NODES / CTILE)      // 512 tiles total
#define NTH     (NT / 2)               // 256 tiles per half
#define RTILE   128
#define WS_REQ  ((size_t)88080384)

typedef __attribute__((ext_vector_type(8))) int   int8v;
typedef __attribute__((ext_vector_type(4))) int   int4v;
typedef __attribute__((ext_vector_type(4))) float float4_;

// fp32 -> fp8 e4m3fn (OCP), RNE, saturating (candidate-gen only).
__device__ __forceinline__ unsigned f2fp8(float f) {
  const unsigned u = __float_as_uint(f);
  const unsigned s = (u >> 24) & 0x80u;
  const unsigned r = u + 0x0007FFFFu + ((u >> 20) & 1u);
  const int e = (int)((r >> 23) & 0xFFu) - 127;
  const unsigned m = (r >> 20) & 7u;
  if (e < -6) {
    float a = __builtin_fabsf(f);
    unsigned q = (unsigned)(a * 512.f + 0.5f);
    if (q > 7u) q = 7u;
    return s | q;
  }
  if (e > 8 || (e == 8 && m > 6u)) return s | 0x7Eu;
  return s | ((unsigned)(e + 7) << 3) | m;
}

__device__ __forceinline__ unsigned uminv(unsigned a, unsigned b) { return a < b ? a : b; }
__device__ __forceinline__ unsigned umaxv(unsigned a, unsigned b) { return a > b ? a : b; }

// unconditional sorted-desc insert of P into T[8]:
// T[s] = max(T[s], min(P, T[s-1]))  ==  med3(P, T[s-1], T[s]) for sorted T.
// s order 7..1 reads pre-update T[s-1]; then T[0] = max(T[0], P).
#define INS8M(T, P) do {                                                       \
    const unsigned _p = (P);                                                   \
    T[7] = umaxv(T[7], uminv(_p, T[6]));                                       \
    T[6] = umaxv(T[6], uminv(_p, T[5]));                                       \
    T[5] = umaxv(T[5], uminv(_p, T[4]));                                       \
    T[4] = umaxv(T[4], uminv(_p, T[3]));                                       \
    T[3] = umaxv(T[3], uminv(_p, T[2]));                                       \
    T[2] = umaxv(T[2], uminv(_p, T[1]));                                       \
    T[1] = umaxv(T[1], uminv(_p, T[0]));                                       \
    T[0] = umaxv(T[0], _p);                                                    \
  } while (0)

// async global->LDS, 16B/lane; LDS dest wave-uniform base + lane*16
__device__ __forceinline__ void gload_lds16(const void* g, void* l) {
  typedef __attribute__((address_space(1))) const unsigned int gu32;
  typedef __attribute__((address_space(3))) unsigned int lu32;
  __builtin_amdgcn_global_load_lds((gu32*)(uintptr_t)g,
                                   (lu32*)(uint32_t)(uintptr_t)l, 16, 0, 0);
}

// ---------------- P: fp32 projections (FROZEN arithmetic) ----------------
__global__ __launch_bounds__(256) void proj_kernel(
    const float* __restrict__ x,
    const float* __restrict__ Wq, const float* __restrict__ bq,
    const float* __restrict__ Wk, const float* __restrict__ bk,
    float* __restrict__ q32, float* __restrict__ k32)
{
  const int tid = threadIdx.x;
  const int rowbase = blockIdx.x * 32;
  const int c = tid;
  const float* Wcol = (c < 128) ? (Wq + c) : (Wk + (c - 128));
  const float bias  = (c < 128) ? bq[c] : bk[c - 128];
  const float* xrow = x + (size_t)rowbase * D_IN;

  float acc[32];
  #pragma unroll
  for (int r = 0; r < 32; ++r) acc[r] = 0.f;

  for (int kc = 0; kc < D_IN; kc += 16) {
    float wv[16];
    #pragma unroll
    for (int u = 0; u < 16; ++u) wv[u] = Wcol[(size_t)(kc + u) * H_DIM];
    #pragma unroll
    for (int r = 0; r < 32; ++r) {
      #pragma unroll
      for (int u = 0; u < 16; ++u)
        acc[r] = fmaf(xrow[(size_t)r * D_IN + kc + u], wv[u], acc[r]);
    }
  }

  float* O = (c < 128) ? q32 : k32;
  const int h = c & 127;
  #pragma unroll 4
  for (int r = 0; r < 32; ++r)
    O[(size_t)(rowbase + r) * H_DIM + h] = acc[r] + bias;
}

// ---------------- Kf8: one-time fp32 -> fp8 (16 elts/thread) ----------------
__global__ __launch_bounds__(256) void kf8_kernel(
    const float* __restrict__ k32, unsigned char* __restrict__ Kf8)
{
  const size_t base = ((size_t)blockIdx.x * 256 + threadIdx.x) * 16;
  int d[4];
  #pragma unroll
  for (int i = 0; i < 4; ++i) {
    const float4 v = *(const float4*)(k32 + base + i * 4);
    d[i] = (int)(f2fp8(v.x) | (f2fp8(v.y) << 8) |
                 (f2fp8(v.z) << 16) | (f2fp8(v.w) << 24));
  }
  *(int4v*)(Kf8 + base) = (int4v){d[0], d[1], d[2], d[3]};
}

// ----- B: fp8 K=128 MFMA sim, column-split, med3 register top-8 ------------
__global__ __launch_bounds__(256, 4) void sim_topk_f8v_kernel(
    const float* __restrict__ q32, const unsigned char* __restrict__ Kf8,
    int* __restrict__ cand)
{
  __shared__ __align__(16) char smem[32768];   // 2 x 16KB fp8 K-tile dbuf

  const int tid  = threadIdx.x;
  const int lane = tid & 63;
  const int w    = tid >> 6;        // wave 0..3, owns rows [w*32, w*32+32)
  const int rgrp = lane >> 4;       // 0..3 (k-group: 32 fp8 elements)
  const int c16  = lane & 15;
  const int rowbase = (blockIdx.x >> 1) * RTILE;
  const int chalf   = blockIdx.x & 1;          // column half
  const int tbase   = chalf * NTH;             // first tile of this half

  // ---- A-frags: fp32 q -> fp8x32 in-register (one-time) ----
  int8v afr[2];
  #pragma unroll
  for (int m = 0; m < 2; ++m) {
    const float* qr = q32 + (size_t)(rowbase + w * 32 + m * 16 + c16) * H_DIM
                      + rgrp * 32;
    int8v a;
    #pragma unroll
    for (int d = 0; d < 8; ++d) {
      const float4 v = *(const float4*)(qr + d * 4);
      a[d] = (int)(f2fp8(v.x) | (f2fp8(v.y) << 8) |
                   (f2fp8(v.z) << 16) | (f2fp8(v.w) << 24));
    }
    afr[m] = a;
  }

  // packed top-8 per owned row: (fp32bits(max(v,0)) & 0xFFFF0000) | local_col
  unsigned tp[8][8];
  #pragma unroll
  for (int ri = 0; ri < 8; ++ri)
    #pragma unroll
    for (int s = 0; s < 8; ++s) tp[ri][s] = 0u;

  // ---- B-read offsets: slot s -> s ^ (row&7), 16B units; row&7 = c16&7 ----
  int rxor[2];
  #pragma unroll
  for (int j = 0; j < 2; ++j)
    rxor[j] = ((rgrp * 2 + j) ^ (c16 & 7)) << 4;

  // ---- gload source offsets: linear LDS dest, inverse-swizzled source ----
  int srcoff[4];
  #pragma unroll
  for (int j = 0; j < 4; ++j) {
    const int L  = (w * 4 + j) * 1024 + lane * 16;
    const int rr = L >> 7;           // tile-local K row (0..127)
    const int sp = (L >> 4) & 7;     // phys slot
    srcoff[j] = rr * 128 + (((sp ^ (rr & 7))) << 4);
  }

  const char* kbytes = (const char*)Kf8;
  auto STAGE = [&](int t, int sel) {   // t relative to tbase
    const char* src = kbytes + (size_t)(tbase + t) * (CTILE * 128);
    char* dst = smem + sel * 16384;
    #pragma unroll
    for (int j = 0; j < 4; ++j)
      gload_lds16(src + srcoff[j], dst + (w * 4 + j) * 1024);
  };

  STAGE(0, 0);
  __syncthreads();   // barrier drains vmcnt: tile 0 ready

  #pragma unroll 1
  for (int t = 0; t < NTH; ++t) {
    const int cur = t & 1;
    if (t + 1 < NTH) STAGE(t + 1, cur ^ 1);   // in flight under the f-loop

    const char* kbase = smem + cur * 16384;
    #pragma unroll
    for (int f = 0; f < 8; ++f) {
      const char* rowp = kbase + (f * 16 + c16) * 128;
      const int4v lo = *(const int4v*)(rowp + rxor[0]);
      const int4v hi = *(const int4v*)(rowp + rxor[1]);
      int8v b;
      b[0] = lo[0]; b[1] = lo[1]; b[2] = lo[2]; b[3] = lo[3];
      b[4] = hi[0]; b[5] = hi[1]; b[6] = hi[2]; b[7] = hi[3];

      float4_ a0 = (float4_){0.f, 0.f, 0.f, 0.f};
      float4_ a1 = (float4_){0.f, 0.f, 0.f, 0.f};
      a0 = __builtin_amdgcn_mfma_scale_f32_16x16x128_f8f6f4(
               afr[0], b, a0, 0, 0, 0, 0x7F7F7F7F, 0, 0x7F7F7F7F);
      a1 = __builtin_amdgcn_mfma_scale_f32_16x16x128_f8f6f4(
               afr[1], b, a1, 0, 0, 0, 0x7F7F7F7F, 0, 0x7F7F7F7F);

      // unconditional med3-insert: ~10 flat VALU per value, no branches.
      // D layout (m89): col = lane&15, row = rgrp*4 + r2.
      const unsigned colb = (unsigned)(t * CTILE + f * 16 + c16);
      #pragma unroll
      for (int r2 = 0; r2 < 4; ++r2) {
        const unsigned p0 =
            (__float_as_uint(fmaxf(a0[r2], 0.f)) & 0xFFFF0000u) | colb;
        INS8M(tp[r2], p0);
        const unsigned p1 =
            (__float_as_uint(fmaxf(a1[r2], 0.f)) & 0xFFFF0000u) | colb;
        INS8M(tp[4 + r2], p1);
      }
    }
    __syncthreads();   // cur reads done; nxt (gload) drained & visible
  }

  // ---- 4-pass merge: 16 lanes x sorted-8 -> top-24 per row (this half) ----
  unsigned* pairs = (unsigned*)smem;      // [32 rows][16 c16][8] = 16 KB
  const int colbase = tbase * CTILE;      // global col = colbase + local
  for (int p = 0; p < 4; ++p) {
    if (w == p) {
      #pragma unroll
      for (int ri = 0; ri < 8; ++ri) {
        const int rl = (ri >> 2) * 16 + rgrp * 4 + (ri & 3);  // 0..31
        #pragma unroll
        for (int s = 0; s < 8; ++s)
          pairs[((size_t)rl * 16 + c16) * 8 + s] = tp[ri][s];
      }
    }
    __syncthreads();
    if (tid < 32) {
      const int row = rowbase + p * 32 + tid;
      int cur[16];
      #pragma unroll
      for (int l = 0; l < 16; ++l) cur[l] = 0;
      for (int it = 0; it < NCH; ++it) {
        unsigned best = 0u; int bl = 0;
        #pragma unroll
        for (int l = 0; l < 16; ++l) {
          const int cq = cur[l] < 8 ? cur[l] : 7;
          const unsigned v =
              (cur[l] < 8) ? pairs[((size_t)tid * 16 + l) * 8 + cq] : 0u;
          if (v > best) { best = v; bl = l; }
        }
        cand[(size_t)row * NC + chalf * NCH + it] =
            colbase + (int)(best & 0xFFFFu);
        #pragma unroll
        for (int l = 0; l < 16; ++l) cur[l] += (l == bl) ? 1 : 0;
      }
    }
    __syncthreads();
  }
}

// ---- R: wave-per-row fp32 rescore (FROZEN chain) + shuffle-argmax top-8 ---
__global__ __launch_bounds__(256) void rescore48w_kernel(
    const float* __restrict__ q32, const float* __restrict__ k32,
    const int* __restrict__ cand, float* __restrict__ out)
{
  const int tid  = threadIdx.x;
  const int lane = tid & 63;
  const int w    = tid >> 6;
  const int rowbase = blockIdx.x * 8;

  #pragma unroll 1
  for (int rr = 0; rr < 2; ++rr) {
    const int row = rowbase + w * 2 + rr;
    float bs = -3.4e38f;
    int   bi = 0x7FFFFFFF;
    if (lane < NC) {
      const int ci = cand[(size_t)row * NC + lane] & (N_NODES - 1);
      const float4* qp = (const float4*)(q32 + (size_t)row * H_DIM);
      const float4* kp = (const float4*)(k32 + (size_t)ci * H_DIM);
      // strict single-accumulator ascending-h fmaf chain (bit-matches golden)
      float s = 0.f;
      #pragma unroll 8
      for (int h4 = 0; h4 < H_DIM / 4; ++h4) {
        const float4 a = qp[h4], b = kp[h4];
        s = fmaf(a.x, b.x, s); s = fmaf(a.y, b.y, s);
        s = fmaf(a.z, b.z, s); s = fmaf(a.w, b.w, s);
      }
      bs = s;
      bi = ci;
    }
    // 8x wave-argmax (score desc, index asc on exact ties)
    #pragma unroll
    for (int o = 0; o < TOPK; ++o) {
      float rs = bs; int ri = bi;
      #pragma unroll
      for (int off = 32; off > 0; off >>= 1) {
        const float os = __shfl_xor(rs, off);
        const int   oi = __shfl_xor(ri, off);
        if (os > rs || (os == rs && oi < ri)) { rs = os; ri = oi; }
      }
      if (lane == 0) {
        out[(size_t)row * TOPK + o] = rs;
        out[(size_t)N_NODES * TOPK + (size_t)row * TOPK + o] = (float)ri;
      }
      if (bs == rs && bi == ri) bs = -3.4e38f;   // retire winner
    }
  }
}

// sentinel: signals "ws too small" with a distinctive absmax signature
__global__ void sentinel_kernel(float* __restrict__ out) {
  const int i = blockIdx.x * 256 + threadIdx.x;
  out[i] = 0.0f;
  out[(size_t)N_NODES * TOPK + i] = 7777.0f;
}

extern "C" void kernel_launch(void* const* d_in, const int* in_sizes, int n_in,
                              void* d_out, int out_size, void* d_ws, size_t ws_size,
                              hipStream_t stream) {
  const float* x  = (const float*)d_in[0];
  const float* Wq = (const float*)d_in[1];
  const float* bq = (const float*)d_in[2];
  const float* Wk = (const float*)d_in[3];
  const float* bk = (const float*)d_in[4];
  float* out = (float*)d_out;

  if (ws_size < WS_REQ) {
    sentinel_kernel<<<N_NODES * TOPK / 256, 256, 0, stream>>>(out);
    return;
  }

  float* q32 = (float*)d_ws;                                      // 33.5 MB
  float* k32 = q32 + (size_t)N_NODES * H_DIM;                     // 33.5 MB
  int* cand  = (int*)((char*)d_ws + (size_t)67108864);            // 12.6 MB
  unsigned char* Kf8 = (unsigned char*)d_ws + (size_t)79691776;   // 8.4 MB

  proj_kernel<<<N_NODES / 32, 256, 0, stream>>>(x, Wq, bq, Wk, bk, q32, k32);
  kf8_kernel<<<(N_NODES * H_DIM / 16) / 256, 256, 0, stream>>>(k32, Kf8);
  sim_topk_f8v_kernel<<<N_NODES / RTILE * 2, 256, 0, stream>>>(q32, Kf8, cand);
  rescore48w_kernel<<<N_NODES / 8, 256, 0, stream>>>(q32, k32, cand, out);
}

// Round 14
// 3341.144 us; speedup vs baseline: 1.2580x; 1.2580x over previous
//
#include <hip/hip_runtime.h>
#include <stdint.h>

// AttentionBasedRewiring: sim = (x@Wq+bq) @ (x@Wk+bk)^T, top-8 per row.
// out[0 .. N*8)     = top-8 scores (fp32, descending)
// out[N*8 .. 2*N*8) = top-8 indices, written as float values
//
// FROZEN (bit-exact vs golden, r5): proj_kernel's fp32 sequential-fmaf
// chain and the rescore fp32 sequential-fmaf chain + stable top-8 select
// (score desc, index asc). Candidates only need to be a superset.
//
// Round 14 = clean A/B vs r12 (1840us): ONLY the insert changes.
//   * r12: inline-asm v_med3_u32 with "v" constraints -> forced AGPR->VGPR
//     shuttle copies around every op (tp lives in AGPRs at VGPR_Count=64).
//   * r14: plain-C T[s]=max(T[s],min(p,T[s-1])) -- compiler may emit
//     med3/min/max VOP3 with DIRECT AGPR operands (no copies).
//   * launch bounds back to (256,2): r13's (256,4) spilled (WRITE 2.2GB).
// Tripwires: WRITE_SIZE >> 13MB => spill; sim ~1840us => theory falsified.
//
// ws: q32 [0,33.5M) | k32 [33.5,67.1M) | cand48 [67.1,79.7M) | Kf8 [79.7,88.1M)

#define N_NODES 65536
#define D_IN    512
#define H_DIM   128
#define TOPK    8
#define NCH     24                     // candidates per column-half
#define NC      48                     // union per row
#define CTILE   128
#define NT      (N_NODES / CTILE)      // 512 tiles total
#define NTH     (NT / 2)               // 256 tiles per half
#define RTILE   128
#define WS_REQ  ((size_t)88080384)

typedef __attribute__((ext_vector_type(8))) int   int8v;
typedef __attribute__((ext_vector_type(4))) int   int4v;
typedef __attribute__((ext_vector_type(4))) float float4_;

// fp32 -> fp8 e4m3fn (OCP), RNE, saturating (candidate-gen only).
__device__ __forceinline__ unsigned f2fp8(float f) {
  const unsigned u = __float_as_uint(f);
  const unsigned s = (u >> 24) & 0x80u;
  const unsigned r = u + 0x0007FFFFu + ((u >> 20) & 1u);
  const int e = (int)((r >> 23) & 0xFFu) - 127;
  const unsigned m = (r >> 20) & 7u;
  if (e < -6) {
    float a = __builtin_fabsf(f);
    unsigned q = (unsigned)(a * 512.f + 0.5f);
    if (q > 7u) q = 7u;
    return s | q;
  }
  if (e > 8 || (e == 8 && m > 6u)) return s | 0x7Eu;
  return s | ((unsigned)(e + 7) << 3) | m;
}

__device__ __forceinline__ unsigned uminv(unsigned a, unsigned b) { return a < b ? a : b; }
__device__ __forceinline__ unsigned umaxv(unsigned a, unsigned b) { return a > b ? a : b; }

// unconditional sorted-desc insert of P into T[8]:
// T[s] = max(T[s], min(P, T[s-1]))  ==  med3(P, T[s-1], T[s]) for sorted T.
// s order 7..1 reads pre-update T[s-1]; then T[0] = max(T[0], P).
#define INS8M(T, P) do {                                                       \
    const unsigned _p = (P);                                                   \
    T[7] = umaxv(T[7], uminv(_p, T[6]));                                       \
    T[6] = umaxv(T[6], uminv(_p, T[5]));                                       \
    T[5] = umaxv(T[5], uminv(_p, T[4]));                                       \
    T[4] = umaxv(T[4], uminv(_p, T[3]));                                       \
    T[3] = umaxv(T[3], uminv(_p, T[2]));                                       \
    T[2] = umaxv(T[2], uminv(_p, T[1]));                                       \
    T[1] = umaxv(T[1], uminv(_p, T[0]));                                       \
    T[0] = umaxv(T[0], _p);                                                    \
  } while (0)

// async global->LDS, 16B/lane; LDS dest wave-uniform base + lane*16
__device__ __forceinline__ void gload_lds16(const void* g, void* l) {
  typedef __attribute__((address_space(1))) const unsigned int gu32;
  typedef __attribute__((address_space(3))) unsigned int lu32;
  __builtin_amdgcn_global_load_lds((gu32*)(uintptr_t)g,
                                   (lu32*)(uint32_t)(uintptr_t)l, 16, 0, 0);
}

// ---------------- P: fp32 projections (FROZEN arithmetic) ----------------
__global__ __launch_bounds__(256) void proj_kernel(
    const float* __restrict__ x,
    const float* __restrict__ Wq, const float* __restrict__ bq,
    const float* __restrict__ Wk, const float* __restrict__ bk,
    float* __restrict__ q32, float* __restrict__ k32)
{
  const int tid = threadIdx.x;
  const int rowbase = blockIdx.x * 32;
  const int c = tid;
  const float* Wcol = (c < 128) ? (Wq + c) : (Wk + (c - 128));
  const float bias  = (c < 128) ? bq[c] : bk[c - 128];
  const float* xrow = x + (size_t)rowbase * D_IN;

  float acc[32];
  #pragma unroll
  for (int r = 0; r < 32; ++r) acc[r] = 0.f;

  for (int kc = 0; kc < D_IN; kc += 16) {
    float wv[16];
    #pragma unroll
    for (int u = 0; u < 16; ++u) wv[u] = Wcol[(size_t)(kc + u) * H_DIM];
    #pragma unroll
    for (int r = 0; r < 32; ++r) {
      #pragma unroll
      for (int u = 0; u < 16; ++u)
        acc[r] = fmaf(xrow[(size_t)r * D_IN + kc + u], wv[u], acc[r]);
    }
  }

  float* O = (c < 128) ? q32 : k32;
  const int h = c & 127;
  #pragma unroll 4
  for (int r = 0; r < 32; ++r)
    O[(size_t)(rowbase + r) * H_DIM + h] = acc[r] + bias;
}

// ---------------- Kf8: one-time fp32 -> fp8 (16 elts/thread) ----------------
__global__ __launch_bounds__(256) void kf8_kernel(
    const float* __restrict__ k32, unsigned char* __restrict__ Kf8)
{
  const size_t base = ((size_t)blockIdx.x * 256 + threadIdx.x) * 16;
  int d[4];
  #pragma unroll
  for (int i = 0; i < 4; ++i) {
    const float4 v = *(const float4*)(k32 + base + i * 4);
    d[i] = (int)(f2fp8(v.x) | (f2fp8(v.y) << 8) |
                 (f2fp8(v.z) << 16) | (f2fp8(v.w) << 24));
  }
  *(int4v*)(Kf8 + base) = (int4v){d[0], d[1], d[2], d[3]};
}

// ----- B: fp8 K=128 MFMA sim, column-split, plain-C med3 top-8 -------------
__global__ __launch_bounds__(256, 2) void sim_topk_f8p_kernel(
    const float* __restrict__ q32, const unsigned char* __restrict__ Kf8,
    int* __restrict__ cand)
{
  __shared__ __align__(16) char smem[32768];   // 2 x 16KB fp8 K-tile dbuf

  const int tid  = threadIdx.x;
  const int lane = tid & 63;
  const int w    = tid >> 6;        // wave 0..3, owns rows [w*32, w*32+32)
  const int rgrp = lane >> 4;       // 0..3 (k-group: 32 fp8 elements)
  const int c16  = lane & 15;
  const int rowbase = (blockIdx.x >> 1) * RTILE;
  const int chalf   = blockIdx.x & 1;          // column half
  const int tbase   = chalf * NTH;             // first tile of this half

  // ---- A-frags: fp32 q -> fp8x32 in-register (one-time) ----
  int8v afr[2];
  #pragma unroll
  for (int m = 0; m < 2; ++m) {
    const float* qr = q32 + (size_t)(rowbase + w * 32 + m * 16 + c16) * H_DIM
                      + rgrp * 32;
    int8v a;
    #pragma unroll
    for (int d = 0; d < 8; ++d) {
      const float4 v = *(const float4*)(qr + d * 4);
      a[d] = (int)(f2fp8(v.x) | (f2fp8(v.y) << 8) |
                   (f2fp8(v.z) << 16) | (f2fp8(v.w) << 24));
    }
    afr[m] = a;
  }

  // packed top-8 per owned row: (fp32bits(max(v,0)) & 0xFFFF0000) | local_col
  unsigned tp[8][8];
  #pragma unroll
  for (int ri = 0; ri < 8; ++ri)
    #pragma unroll
    for (int s = 0; s < 8; ++s) tp[ri][s] = 0u;

  // ---- B-read offsets: slot s -> s ^ (row&7), 16B units; row&7 = c16&7 ----
  int rxor[2];
  #pragma unroll
  for (int j = 0; j < 2; ++j)
    rxor[j] = ((rgrp * 2 + j) ^ (c16 & 7)) << 4;

  // ---- gload source offsets: linear LDS dest, inverse-swizzled source ----
  int srcoff[4];
  #pragma unroll
  for (int j = 0; j < 4; ++j) {
    const int L  = (w * 4 + j) * 1024 + lane * 16;
    const int rr = L >> 7;           // tile-local K row (0..127)
    const int sp = (L >> 4) & 7;     // phys slot
    srcoff[j] = rr * 128 + (((sp ^ (rr & 7))) << 4);
  }

  const char* kbytes = (const char*)Kf8;
  auto STAGE = [&](int t, int sel) {   // t relative to tbase
    const char* src = kbytes + (size_t)(tbase + t) * (CTILE * 128);
    char* dst = smem + sel * 16384;
    #pragma unroll
    for (int j = 0; j < 4; ++j)
      gload_lds16(src + srcoff[j], dst + (w * 4 + j) * 1024);
  };

  STAGE(0, 0);
  __syncthreads();   // barrier drains vmcnt: tile 0 ready

  #pragma unroll 1
  for (int t = 0; t < NTH; ++t) {
    const int cur = t & 1;
    if (t + 1 < NTH) STAGE(t + 1, cur ^ 1);   // in flight under the f-loop

    const char* kbase = smem + cur * 16384;
    #pragma unroll
    for (int f = 0; f < 8; ++f) {
      const char* rowp = kbase + (f * 16 + c16) * 128;
      const int4v lo = *(const int4v*)(rowp + rxor[0]);
      const int4v hi = *(const int4v*)(rowp + rxor[1]);
      int8v b;
      b[0] = lo[0]; b[1] = lo[1]; b[2] = lo[2]; b[3] = lo[3];
      b[4] = hi[0]; b[5] = hi[1]; b[6] = hi[2]; b[7] = hi[3];

      float4_ a0 = (float4_){0.f, 0.f, 0.f, 0.f};
      float4_ a1 = (float4_){0.f, 0.f, 0.f, 0.f};
      a0 = __builtin_amdgcn_mfma_scale_f32_16x16x128_f8f6f4(
               afr[0], b, a0, 0, 0, 0, 0x7F7F7F7F, 0, 0x7F7F7F7F);
      a1 = __builtin_amdgcn_mfma_scale_f32_16x16x128_f8f6f4(
               afr[1], b, a1, 0, 0, 0, 0x7F7F7F7F, 0, 0x7F7F7F7F);

      // unconditional branchless insert: min/max VOP3 (direct AGPR operands).
      // D layout (m89): col = lane&15, row = rgrp*4 + r2.
      const unsigned colb = (unsigned)(t * CTILE + f * 16 + c16);
      #pragma unroll
      for (int r2 = 0; r2 < 4; ++r2) {
        const unsigned p0 =
            (__float_as_uint(fmaxf(a0[r2], 0.f)) & 0xFFFF0000u) | colb;
        INS8M(tp[r2], p0);
        const unsigned p1 =
            (__float_as_uint(fmaxf(a1[r2], 0.f)) & 0xFFFF0000u) | colb;
        INS8M(tp[4 + r2], p1);
      }
    }
    __syncthreads();   // cur reads done; nxt (gload) drained & visible
  }

  // ---- 4-pass merge: 16 lanes x sorted-8 -> top-24 per row (this half) ----
  unsigned* pairs = (unsigned*)smem;      // [32 rows][16 c16][8] = 16 KB
  const int colbase = tbase * CTILE;      // global col = colbase + local
  for (int p = 0; p < 4; ++p) {
    if (w == p) {
      #pragma unroll
      for (int ri = 0; ri < 8; ++ri) {
        const int rl = (ri >> 2) * 16 + rgrp * 4 + (ri & 3);  // 0..31
        #pragma unroll
        for (int s = 0; s < 8; ++s)
          pairs[((size_t)rl * 16 + c16) * 8 + s] = tp[ri][s];
      }
    }
    __syncthreads();
    if (tid < 32) {
      const int row = rowbase + p * 32 + tid;
      int cur[16];
      #pragma unroll
      for (int l = 0; l < 16; ++l) cur[l] = 0;
      for (int it = 0; it < NCH; ++it) {
        unsigned best = 0u; int bl = 0;
        #pragma unroll
        for (int l = 0; l < 16; ++l) {
          const int cq = cur[l] < 8 ? cur[l] : 7;
          const unsigned v =
              (cur[l] < 8) ? pairs[((size_t)tid * 16 + l) * 8 + cq] : 0u;
          if (v > best) { best = v; bl = l; }
        }
        cand[(size_t)row * NC + chalf * NCH + it] =
            colbase + (int)(best & 0xFFFFu);
        #pragma unroll
        for (int l = 0; l < 16; ++l) cur[l] += (l == bl) ? 1 : 0;
      }
    }
    __syncthreads();
  }
}

// ---- R: wave-per-row fp32 rescore (FROZEN chain) + shuffle-argmax top-8 ---
__global__ __launch_bounds__(256) void rescore48w_kernel(
    const float* __restrict__ q32, const float* __restrict__ k32,
    const int* __restrict__ cand, float* __restrict__ out)
{
  const int tid  = threadIdx.x;
  const int lane = tid & 63;
  const int w    = tid >> 6;
  const int rowbase = blockIdx.x * 8;

  #pragma unroll 1
  for (int rr = 0; rr < 2; ++rr) {
    const int row = rowbase + w * 2 + rr;
    float bs = -3.4e38f;
    int   bi = 0x7FFFFFFF;
    if (lane < NC) {
      const int ci = cand[(size_t)row * NC + lane] & (N_NODES - 1);
      const float4* qp = (const float4*)(q32 + (size_t)row * H_DIM);
      const float4* kp = (const float4*)(k32 + (size_t)ci * H_DIM);
      // strict single-accumulator ascending-h fmaf chain (bit-matches golden)
      float s = 0.f;
      #pragma unroll 8
      for (int h4 = 0; h4 < H_DIM / 4; ++h4) {
        const float4 a = qp[h4], b = kp[h4];
        s = fmaf(a.x, b.x, s); s = fmaf(a.y, b.y, s);
        s = fmaf(a.z, b.z, s); s = fmaf(a.w, b.w, s);
      }
      bs = s;
      bi = ci;
    }
    // 8x wave-argmax (score desc, index asc on exact ties)
    #pragma unroll
    for (int o = 0; o < TOPK; ++o) {
      float rs = bs; int ri = bi;
      #pragma unroll
      for (int off = 32; off > 0; off >>= 1) {
        const float os = __shfl_xor(rs, off);
        const int   oi = __shfl_xor(ri, off);
        if (os > rs || (os == rs && oi < ri)) { rs = os; ri = oi; }
      }
      if (lane == 0) {
        out[(size_t)row * TOPK + o] = rs;
        out[(size_t)N_NODES * TOPK + (size_t)row * TOPK + o] = (float)ri;
      }
      if (bs == rs && bi == ri) bs = -3.4e38f;   // retire winner
    }
  }
}

// sentinel: signals "ws too small" with a distinctive absmax signature
__global__ void sentinel_kernel(float* __restrict__ out) {
  const int i = blockIdx.x * 256 + threadIdx.x;
  out[i] = 0.0f;
  out[(size_t)N_NODES * TOPK + i] = 7777.0f;
}

extern "C" void kernel_launch(void* const* d_in, const int* in_sizes, int n_in,
                              void* d_out, int out_size, void* d_ws, size_t ws_size,
                              hipStream_t stream) {
  const float* x  = (const float*)d_in[0];
  const float* Wq = (const float*)d_in[1];
  const float* bq = (const float*)d_in[2];
  const float* Wk = (const float*)d_in[3];
  const float* bk = (const float*)d_in[4];
  float* out = (float*)d_out;

  if (ws_size < WS_REQ) {
    sentinel_kernel<<<N_NODES * TOPK / 256, 256, 0, stream>>>(out);
    return;
  }

  float* q32 = (float*)d_ws;                                      // 33.5 MB
  float* k32 = q32 + (size_t)N_NODES * H_DIM;                     // 33.5 MB
  int* cand  = (int*)((char*)d_ws + (size_t)67108864);            // 12.6 MB
  unsigned char* Kf8 = (unsigned char*)d_ws + (size_t)79691776;   // 8.4 MB

  proj_kernel<<<N_NODES / 32, 256, 0, stream>>>(x, Wq, bq, Wk, bk, q32, k32);
  kf8_kernel<<<(N_NODES * H_DIM / 16) / 256, 256, 0, stream>>>(k32, Kf8);
  sim_topk_f8p_kernel<<<N_NODES / RTILE * 2, 256, 0, stream>>>(q32, Kf8, cand);
  rescore48w_kernel<<<N_NODES / 8, 256, 0, stream>>>(q32, k32, cand, out);
}

// Round 15
// 2287.515 us; speedup vs baseline: 1.8374x; 1.4606x over previous
//
#include <hip/hip_runtime.h>
#include <stdint.h>

// AttentionBasedRewiring: sim = (x@Wq+bq) @ (x@Wk+bk)^T, top-8 per row.
// out[0 .. N*8)     = top-8 scores (fp32, descending)
// out[N*8 .. 2*N*8) = top-8 indices, written as float values
//
// FROZEN (bit-exact vs golden, r5): proj_kernel's fp32 sequential-fmaf
// chain and the rescore fp32 sequential-fmaf chain + stable top-8 select
// (score desc, index asc). Candidates only need to be a superset.
//
// Round 15: PAIR-MAX pre-reduction (r12 base = best sim, 1840us, asm med3).
//   * EXACT superset lemma: the k-th largest single (k<=8) has <=7 pairs
//     with larger pair-max => its pair is in the stream's top-8 pairs.
//   * f-loop processes column-pairs (f=2fp, 2fp+1): 1 v_max_f32 merges the
//     two cols, then ONE packed med3-insert per pair -> insert VALU halves.
//   * candidate = pair-id (14 bit local); rescore expands each pair to both
//     columns: 96 exact fp32 dots per row, one WAVE per row, 2 slots/lane,
//     8x shuffle-argmax (score desc, col asc), retire by unique col.
//   * everything else identical to r12 (fp8 K=128 MFMA, gload_lds dbuf,
//     slot-XOR swizzle, column-split grid 1024, lb(256,2)).
//
// ws: q32 [0,33.5M) | k32 [33.5,67.1M) | cand48 [67.1,79.7M) | Kf8 [79.7,88.1M)

#define N_NODES 65536
#define D_IN    512
#define H_DIM   128
#define TOPK    8
#define NCH     24                     // pair-candidates per column-half
#define NC      48                     // pair union per row (=> 96 columns)
#define CTILE   128
#define NT      (N_NODES / CTILE)      // 512 tiles total
#define NTH     (NT / 2)               // 256 tiles per half
#define RTILE   128
#define WS_REQ  ((size_t)88080384)

typedef __attribute__((ext_vector_type(8))) int   int8v;
typedef __attribute__((ext_vector_type(4))) int   int4v;
typedef __attribute__((ext_vector_type(4))) float float4_;

// fp32 -> fp8 e4m3fn (OCP), RNE, saturating (candidate-gen only).
__device__ __forceinline__ unsigned f2fp8(float f) {
  const unsigned u = __float_as_uint(f);
  const unsigned s = (u >> 24) & 0x80u;
  const unsigned r = u + 0x0007FFFFu + ((u >> 20) & 1u);
  const int e = (int)((r >> 23) & 0xFFu) - 127;
  const unsigned m = (r >> 20) & 7u;
  if (e < -6) {
    float a = __builtin_fabsf(f);
    unsigned q = (unsigned)(a * 512.f + 0.5f);
    if (q > 7u) q = 7u;
    return s | q;
  }
  if (e > 8 || (e == 8 && m > 6u)) return s | 0x7Eu;
  return s | ((unsigned)(e + 7) << 3) | m;
}

// median-of-3 unsigned (r12-proven fastest insert primitive on this kernel)
__device__ __forceinline__ unsigned med3u(unsigned a, unsigned b, unsigned c) {
  unsigned d;
  asm("v_med3_u32 %0, %1, %2, %3" : "=v"(d) : "v"(a), "v"(b), "v"(c));
  return d;
}

// unconditional sorted-desc insert of P into T[8] (all static indices)
#define INS8M(T, P) do {                                                       \
    const unsigned _p = (P);                                                   \
    T[7] = med3u(_p, T[6], T[7]);                                              \
    T[6] = med3u(_p, T[5], T[6]);                                              \
    T[5] = med3u(_p, T[4], T[5]);                                              \
    T[4] = med3u(_p, T[3], T[4]);                                              \
    T[3] = med3u(_p, T[2], T[3]);                                              \
    T[2] = med3u(_p, T[1], T[2]);                                              \
    T[1] = med3u(_p, T[0], T[1]);                                              \
    T[0] = (T[0] > _p) ? T[0] : _p;                                            \
  } while (0)

// async global->LDS, 16B/lane; LDS dest wave-uniform base + lane*16
__device__ __forceinline__ void gload_lds16(const void* g, void* l) {
  typedef __attribute__((address_space(1))) const unsigned int gu32;
  typedef __attribute__((address_space(3))) unsigned int lu32;
  __builtin_amdgcn_global_load_lds((gu32*)(uintptr_t)g,
                                   (lu32*)(uint32_t)(uintptr_t)l, 16, 0, 0);
}

// ---------------- P: fp32 projections (FROZEN arithmetic) ----------------
__global__ __launch_bounds__(256) void proj_kernel(
    const float* __restrict__ x,
    const float* __restrict__ Wq, const float* __restrict__ bq,
    const float* __restrict__ Wk, const float* __restrict__ bk,
    float* __restrict__ q32, float* __restrict__ k32)
{
  const int tid = threadIdx.x;
  const int rowbase = blockIdx.x * 32;
  const int c = tid;
  const float* Wcol = (c < 128) ? (Wq + c) : (Wk + (c - 128));
  const float bias  = (c < 128) ? bq[c] : bk[c - 128];
  const float* xrow = x + (size_t)rowbase * D_IN;

  float acc[32];
  #pragma unroll
  for (int r = 0; r < 32; ++r) acc[r] = 0.f;

  for (int kc = 0; kc < D_IN; kc += 16) {
    float wv[16];
    #pragma unroll
    for (int u = 0; u < 16; ++u) wv[u] = Wcol[(size_t)(kc + u) * H_DIM];
    #pragma unroll
    for (int r = 0; r < 32; ++r) {
      #pragma unroll
      for (int u = 0; u < 16; ++u)
        acc[r] = fmaf(xrow[(size_t)r * D_IN + kc + u], wv[u], acc[r]);
    }
  }

  float* O = (c < 128) ? q32 : k32;
  const int h = c & 127;
  #pragma unroll 4
  for (int r = 0; r < 32; ++r)
    O[(size_t)(rowbase + r) * H_DIM + h] = acc[r] + bias;
}

// ---------------- Kf8: one-time fp32 -> fp8 (16 elts/thread) ----------------
__global__ __launch_bounds__(256) void kf8_kernel(
    const float* __restrict__ k32, unsigned char* __restrict__ Kf8)
{
  const size_t base = ((size_t)blockIdx.x * 256 + threadIdx.x) * 16;
  int d[4];
  #pragma unroll
  for (int i = 0; i < 4; ++i) {
    const float4 v = *(const float4*)(k32 + base + i * 4);
    d[i] = (int)(f2fp8(v.x) | (f2fp8(v.y) << 8) |
                 (f2fp8(v.z) << 16) | (f2fp8(v.w) << 24));
  }
  *(int4v*)(Kf8 + base) = (int4v){d[0], d[1], d[2], d[3]};
}

// ----- B: fp8 K=128 MFMA sim, column-split, pair-max med3 top-8 ------------
__global__ __launch_bounds__(256, 2) void sim_topk_f8pr_kernel(
    const float* __restrict__ q32, const unsigned char* __restrict__ Kf8,
    int* __restrict__ cand)
{
  __shared__ __align__(16) char smem[32768];   // 2 x 16KB fp8 K-tile dbuf

  const int tid  = threadIdx.x;
  const int lane = tid & 63;
  const int w    = tid >> 6;        // wave 0..3, owns rows [w*32, w*32+32)
  const int rgrp = lane >> 4;       // 0..3 (k-group: 32 fp8 elements)
  const int c16  = lane & 15;
  const int rowbase = (blockIdx.x >> 1) * RTILE;
  const int chalf   = blockIdx.x & 1;          // column half
  const int tbase   = chalf * NTH;             // first tile of this half

  // ---- A-frags: fp32 q -> fp8x32 in-register (one-time) ----
  int8v afr[2];
  #pragma unroll
  for (int m = 0; m < 2; ++m) {
    const float* qr = q32 + (size_t)(rowbase + w * 32 + m * 16 + c16) * H_DIM
                      + rgrp * 32;
    int8v a;
    #pragma unroll
    for (int d = 0; d < 8; ++d) {
      const float4 v = *(const float4*)(qr + d * 4);
      a[d] = (int)(f2fp8(v.x) | (f2fp8(v.y) << 8) |
                   (f2fp8(v.z) << 16) | (f2fp8(v.w) << 24));
    }
    afr[m] = a;
  }

  // packed top-8 PAIRS per owned row: (fp32bits(max(pm,0)) & 0xFFFF0000)|pid
  unsigned tp[8][8];
  #pragma unroll
  for (int ri = 0; ri < 8; ++ri)
    #pragma unroll
    for (int s = 0; s < 8; ++s) tp[ri][s] = 0u;

  // ---- B-read offsets: slot s -> s ^ (row&7), 16B units; row&7 = c16&7 ----
  int rxor[2];
  #pragma unroll
  for (int j = 0; j < 2; ++j)
    rxor[j] = ((rgrp * 2 + j) ^ (c16 & 7)) << 4;

  // ---- gload source offsets: linear LDS dest, inverse-swizzled source ----
  int srcoff[4];
  #pragma unroll
  for (int j = 0; j < 4; ++j) {
    const int L  = (w * 4 + j) * 1024 + lane * 16;
    const int rr = L >> 7;           // tile-local K row (0..127)
    const int sp = (L >> 4) & 7;     // phys slot
    srcoff[j] = rr * 128 + (((sp ^ (rr & 7))) << 4);
  }

  const char* kbytes = (const char*)Kf8;
  auto STAGE = [&](int t, int sel) {   // t relative to tbase
    const char* src = kbytes + (size_t)(tbase + t) * (CTILE * 128);
    char* dst = smem + sel * 16384;
    #pragma unroll
    for (int j = 0; j < 4; ++j)
      gload_lds16(src + srcoff[j], dst + (w * 4 + j) * 1024);
  };

  STAGE(0, 0);
  __syncthreads();   // barrier drains vmcnt: tile 0 ready

  #pragma unroll 1
  for (int t = 0; t < NTH; ++t) {
    const int cur = t & 1;
    if (t + 1 < NTH) STAGE(t + 1, cur ^ 1);   // in flight under the fp-loop

    const char* kbase = smem + cur * 16384;
    #pragma unroll
    for (int fp = 0; fp < 4; ++fp) {
      // ---- column f0 = 2*fp ----
      const char* rowp0 = kbase + ((2 * fp) * 16 + c16) * 128;
      const int4v lo0 = *(const int4v*)(rowp0 + rxor[0]);
      const int4v hi0 = *(const int4v*)(rowp0 + rxor[1]);
      int8v b0;
      b0[0] = lo0[0]; b0[1] = lo0[1]; b0[2] = lo0[2]; b0[3] = lo0[3];
      b0[4] = hi0[0]; b0[5] = hi0[1]; b0[6] = hi0[2]; b0[7] = hi0[3];
      float4_ a0x = (float4_){0.f, 0.f, 0.f, 0.f};
      float4_ a1x = (float4_){0.f, 0.f, 0.f, 0.f};
      a0x = __builtin_amdgcn_mfma_scale_f32_16x16x128_f8f6f4(
                afr[0], b0, a0x, 0, 0, 0, 0x7F7F7F7F, 0, 0x7F7F7F7F);
      a1x = __builtin_amdgcn_mfma_scale_f32_16x16x128_f8f6f4(
                afr[1], b0, a1x, 0, 0, 0, 0x7F7F7F7F, 0, 0x7F7F7F7F);

      // ---- column f1 = 2*fp+1 ----
      const char* rowp1 = kbase + ((2 * fp + 1) * 16 + c16) * 128;
      const int4v lo1 = *(const int4v*)(rowp1 + rxor[0]);
      const int4v hi1 = *(const int4v*)(rowp1 + rxor[1]);
      int8v b1;
      b1[0] = lo1[0]; b1[1] = lo1[1]; b1[2] = lo1[2]; b1[3] = lo1[3];
      b1[4] = hi1[0]; b1[5] = hi1[1]; b1[6] = hi1[2]; b1[7] = hi1[3];
      float4_ a0y = (float4_){0.f, 0.f, 0.f, 0.f};
      float4_ a1y = (float4_){0.f, 0.f, 0.f, 0.f};
      a0y = __builtin_amdgcn_mfma_scale_f32_16x16x128_f8f6f4(
                afr[0], b1, a0y, 0, 0, 0, 0x7F7F7F7F, 0, 0x7F7F7F7F);
      a1y = __builtin_amdgcn_mfma_scale_f32_16x16x128_f8f6f4(
                afr[1], b1, a1y, 0, 0, 0, 0x7F7F7F7F, 0, 0x7F7F7F7F);

      // pair-id: pid = t*64 + fp*16 + c16  (< 16384, 14 bits)
      const unsigned pid = (unsigned)(t * 64 + fp * 16 + c16);
      // D layout (m89): col = lane&15, row = rgrp*4 + r2.
      #pragma unroll
      for (int r2 = 0; r2 < 4; ++r2) {
        const float m0 = fmaxf(a0x[r2], a0y[r2]);          // pair-max
        const unsigned p0 =
            (__float_as_uint(fmaxf(m0, 0.f)) & 0xFFFF0000u) | pid;
        INS8M(tp[r2], p0);
        const float m1 = fmaxf(a1x[r2], a1y[r2]);
        const unsigned p1 =
            (__float_as_uint(fmaxf(m1, 0.f)) & 0xFFFF0000u) | pid;
        INS8M(tp[4 + r2], p1);
      }
    }
    __syncthreads();   // cur reads done; nxt (gload) drained & visible
  }

  // ---- 4-pass merge: 16 lanes x sorted-8 -> top-24 pairs per row-half ----
  unsigned* pairs = (unsigned*)smem;      // [32 rows][16 c16][8] = 16 KB
  for (int p = 0; p < 4; ++p) {
    if (w == p) {
      #pragma unroll
      for (int ri = 0; ri < 8; ++ri) {
        const int rl = (ri >> 2) * 16 + rgrp * 4 + (ri & 3);  // 0..31
        #pragma unroll
        for (int s = 0; s < 8; ++s)
          pairs[((size_t)rl * 16 + c16) * 8 + s] = tp[ri][s];
      }
    }
    __syncthreads();
    if (tid < 32) {
      const int row = rowbase + p * 32 + tid;
      int cur[16];
      #pragma unroll
      for (int l = 0; l < 16; ++l) cur[l] = 0;
      for (int it = 0; it < NCH; ++it) {
        unsigned best = 0u; int bl = 0;
        #pragma unroll
        for (int l = 0; l < 16; ++l) {
          const int cq = cur[l] < 8 ? cur[l] : 7;
          const unsigned v =
              (cur[l] < 8) ? pairs[((size_t)tid * 16 + l) * 8 + cq] : 0u;
          if (v > best) { best = v; bl = l; }
        }
        // store GLOBAL pair id: chalf<<14 | local pid
        cand[(size_t)row * NC + chalf * NCH + it] =
            (chalf << 14) | (int)(best & 0x3FFFu);
        #pragma unroll
        for (int l = 0; l < 16; ++l) cur[l] += (l == bl) ? 1 : 0;
      }
    }
    __syncthreads();
  }
}

// -- R: wave-per-row rescore (FROZEN chain) of 48 pairs = 96 cols + top-8 ---
__global__ __launch_bounds__(256) void rescore96w_kernel(
    const float* __restrict__ q32, const float* __restrict__ k32,
    const int* __restrict__ cand, float* __restrict__ out)
{
  const int tid  = threadIdx.x;
  const int lane = tid & 63;
  const int w    = tid >> 6;
  const int row  = blockIdx.x * 4 + w;        // one wave per row

  const float4* qp = (const float4*)(q32 + (size_t)row * H_DIM);

  // lane L holds cols 2 slots: slot0 = col j=L, slot1 = col j=L+64 (L<32)
  float s0 = -3.4e38f, s1 = -3.4e38f;
  int   c0 = -1,       c1 = -1;

  #pragma unroll
  for (int sl = 0; sl < 2; ++sl) {
    const int j = lane + sl * 64;             // col slot index 0..95
    if (j < 2 * NC && (sl == 0 || lane < 2 * NC - 64)) {
      const int gpid = cand[(size_t)row * NC + (j >> 1)];
      const int ch = (gpid >> 14) & 1, pl = gpid & 16383;
      const int tt = pl >> 6, rr = pl & 63;
      const int colA = ch * 32768 + tt * 128 + ((rr >> 4) << 5) + (rr & 15);
      const int col  = colA + (j & 1) * 16;
      const float4* kp = (const float4*)(k32 + (size_t)col * H_DIM);
      // strict single-accumulator ascending-h fmaf chain (FROZEN)
      float s = 0.f;
      #pragma unroll 8
      for (int h4 = 0; h4 < H_DIM / 4; ++h4) {
        const float4 a = qp[h4], b = kp[h4];
        s = fmaf(a.x, b.x, s); s = fmaf(a.y, b.y, s);
        s = fmaf(a.z, b.z, s); s = fmaf(a.w, b.w, s);
      }
      if (sl == 0) { s0 = s; c0 = col; } else { s1 = s; c1 = col; }
    }
  }

  // 8x wave-argmax (score desc, col asc on exact ties); cols unique.
  #pragma unroll
  for (int o = 0; o < TOPK; ++o) {
    float ls; int lc;
    if (s0 > s1 || (s0 == s1 && (unsigned)c0 < (unsigned)c1)) { ls = s0; lc = c0; }
    else                                                      { ls = s1; lc = c1; }
    #pragma unroll
    for (int off = 32; off > 0; off >>= 1) {
      const float os = __shfl_xor(ls, off);
      const int   oc = __shfl_xor(lc, off);
      if (os > ls || (os == ls && (unsigned)oc < (unsigned)lc)) { ls = os; lc = oc; }
    }
    if (lane == 0) {
      out[(size_t)row * TOPK + o] = ls;
      out[(size_t)N_NODES * TOPK + (size_t)row * TOPK + o] = (float)lc;
    }
    if (lc == c0) s0 = -3.4e38f;   // retire winner (cols unique)
    if (lc == c1) s1 = -3.4e38f;
  }
}

// sentinel: signals "ws too small" with a distinctive absmax signature
__global__ void sentinel_kernel(float* __restrict__ out) {
  const int i = blockIdx.x * 256 + threadIdx.x;
  out[i] = 0.0f;
  out[(size_t)N_NODES * TOPK + i] = 7777.0f;
}

extern "C" void kernel_launch(void* const* d_in, const int* in_sizes, int n_in,
                              void* d_out, int out_size, void* d_ws, size_t ws_size,
                              hipStream_t stream) {
  const float* x  = (const float*)d_in[0];
  const float* Wq = (const float*)d_in[1];
  const float* bq = (const float*)d_in[2];
  const float* Wk = (const float*)d_in[3];
  const float* bk = (const float*)d_in[4];
  float* out = (float*)d_out;

  if (ws_size < WS_REQ) {
    sentinel_kernel<<<N_NODES * TOPK / 256, 256, 0, stream>>>(out);
    return;
  }

  float* q32 = (float*)d_ws;                                      // 33.5 MB
  float* k32 = q32 + (size_t)N_NODES * H_DIM;                     // 33.5 MB
  int* cand  = (int*)((char*)d_ws + (size_t)67108864);            // 12.6 MB
  unsigned char* Kf8 = (unsigned char*)d_ws + (size_t)79691776;   // 8.4 MB

  proj_kernel<<<N_NODES / 32, 256, 0, stream>>>(x, Wq, bq, Wk, bk, q32, k32);
  kf8_kernel<<<(N_NODES * H_DIM / 16) / 256, 256, 0, stream>>>(k32, Kf8);
  sim_topk_f8pr_kernel<<<N_NODES / RTILE * 2, 256, 0, stream>>>(q32, Kf8, cand);
  rescore96w_kernel<<<N_NODES / 4, 256, 0, stream>>>(q32, k32, cand, out);
}